// Round 9
// baseline (31.280 us; speedup 1.0000x reference)
//
#include <hip/hip_runtime.h>

// Problem constants (from the reference file)
constexpr int kC = 3;
constexpr int kH = 2048;
constexpr int kW = 2048;
constexpr int kNB = 256;      // N_BOXES
constexpr int kHeight = 32;   // HEIGHT

typedef float f32x4 __attribute__((ext_vector_type(4)));

// Shared per-box width computation — MUST be bit-identical in both kernels
// (IEEE, no contraction) so the active/zero partition is consistent.
__device__ __forceinline__ int box_width(const float* __restrict__ boxes,
                                         float s, int b) {
#pragma clang fp contract(off)
    const float* bx = boxes + b * 8;
    const float p0x = bx[0] / s, p0y = bx[1] / s;
    const float p1x = bx[2] / s, p1y = bx[3] / s;
    const float p2x = bx[4] / s, p2y = bx[5] / s;
    const float hdx = p2x - p1x, hdy = p2y - p1y;
    const float h_dist = sqrtf(hdx * hdx + hdy * hdy);
    const float wdx = p1x - p0x, wdy = p1y - p0y;
    const float w_dist = sqrtf(wdx * wdx + wdy * wdy);
    return (int)(32.0f * w_dist / fmaxf(h_dist, 1e-6f));
}

// Phase 1: pure-write zero-fill of the masked suffix [ceil(width/4)*4, max_w)
// of every row, fill-kernel style (256 threads, coalesced dwordx4 sweeps).
// Also writes the widths_out tail. Disjoint from phase 2's region.
__global__ __launch_bounds__(256) void zerofill_kernel(
    const float* __restrict__ boxes,
    const float* __restrict__ scale,
    float* __restrict__ out,
    int max_w, int nq)
{
    const int bc = blockIdx.x;            // 0..767 = (box, channel)
    const int b = bc / 3;
    const int ch = bc - b * 3;

    const float s = scale[0];
    const int width = box_width(boxes, s, b);
    const int qstart = (width + 3) >> 2;  // first all-zero quad

    if (ch == 0 && threadIdx.x == 0) {
        out[(size_t)kNB * kC * kHeight * max_w + b] = (float)(width / 8 * 8 + 8);
    }

    float* plane = out + (size_t)(b * kC + ch) * kHeight * max_w;
    const f32x4 z = {0.f, 0.f, 0.f, 0.f};
#pragma unroll 4
    for (int r = 0; r < kHeight; ++r) {
        float* rowp = plane + (size_t)r * max_w;
        for (int q = qstart + threadIdx.x; q < nq; q += 256) {
            *(f32x4*)(rowp + q * 4) = z;
        }
    }
}

// Phase 2: active region only (quads with c0 < width). R3-champion structure:
// 64-thread blocks, 4 cols/thread, 3 channels/thread, bit-exact reference math.
__global__ __launch_bounds__(64) void extract_kernel(
    const float* __restrict__ img,
    const float* __restrict__ boxes,
    const float* __restrict__ scale,
    float* __restrict__ out,
    int max_w)
{
#pragma clang fp contract(off)
    const int r = blockIdx.y;
    const int b = blockIdx.z;
    const int c0 = (blockIdx.x * 64 + threadIdx.x) * 4;

    const float s = scale[0];
    const float* bx = boxes + b * 8;
    const float p0x = bx[0] / s, p0y = bx[1] / s;
    const float p1x = bx[2] / s, p1y = bx[3] / s;
    const float p2x = bx[4] / s, p2y = bx[5] / s;
    const float p3x = bx[6] / s, p3y = bx[7] / s;

    const float hdx = p2x - p1x, hdy = p2y - p1y;
    const float h_dist = sqrtf(hdx * hdx + hdy * hdy);
    const float wdx = p1x - p0x, wdy = p1y - p0y;
    const float w_dist = sqrtf(wdx * wdx + wdy * wdy);
    const int width = (int)(32.0f * w_dist / fmaxf(h_dist, 1e-6f));
    const float curr_w = (float)width;

    if (c0 >= width) return;              // masked region handled by phase 1

    const size_t ch_stride = (size_t)kHeight * max_w;
    const size_t obase = (((size_t)b * kC) * (size_t)kHeight + (size_t)r) * (size_t)max_w + (size_t)c0;

    f32x4 o0 = {0.f, 0.f, 0.f, 0.f};
    f32x4 o1 = {0.f, 0.f, 0.f, 0.f};
    f32x4 o2 = {0.f, 0.f, 0.f, 0.f};

    const float y = (float)r / 31.0f;
    const float omy = 1.0f - y;
    const float xden = fmaxf(curr_w - 1.0f, 1.0f);
#pragma unroll
    for (int j = 0; j < 4; ++j) {
        const float cf = (float)(c0 + j);
        if (cf < curr_w) {
            const float x = cf / xden;
            const float omx = 1.0f - x;
            const float w00 = omx * omy;
            const float w10 = x * omy;
            const float w11 = x * y;
            const float w01 = omx * y;
            const float res_x = w00 * p0x + w10 * p1x + w11 * p2x + w01 * p3x;
            const float res_y = w00 * p0y + w10 * p1y + w11 * p2y + w01 * p3y;

            const float grid_c = res_x / 2047.0f * 2.0f - 1.0f;
            const float grid_r = res_y / 2047.0f * 2.0f - 1.0f;
            const float fix = rintf((grid_c + 1.0f) * 2047.0f * 0.5f);
            const float fiy = rintf((grid_r + 1.0f) * 2047.0f * 0.5f);
            const bool inb = (fix >= 0.0f) && (fix <= 2047.0f) &&
                             (fiy >= 0.0f) && (fiy <= 2047.0f);
            const int ixc = (int)fminf(fmaxf(fix, 0.0f), 2047.0f);
            const int iyc = (int)fminf(fmaxf(fiy, 0.0f), 2047.0f);

            const size_t ipix = (size_t)iyc * kW + (size_t)ixc;
            const float v0 = img[ipix];
            const float v1 = img[(size_t)kH * kW + ipix];
            const float v2 = img[2 * (size_t)kH * kW + ipix];
            o0[j] = inb ? v0 : 0.0f;
            o1[j] = inb ? v1 : 0.0f;
            o2[j] = inb ? v2 : 0.0f;
        }
    }

    // Boundary quad keeps in-quad zeros (j-loop leaves them 0) — phase 1
    // starts at the NEXT quad, so regions are exactly disjoint.
    *(f32x4*)(out + obase) = o0;
    *(f32x4*)(out + obase + ch_stride) = o1;
    *(f32x4*)(out + obase + 2 * ch_stride) = o2;
}

extern "C" void kernel_launch(void* const* d_in, const int* in_sizes, int n_in,
                              void* d_out, int out_size, void* d_ws, size_t ws_size,
                              hipStream_t stream) {
    const float* img   = (const float*)d_in[0];
    const float* boxes = (const float*)d_in[1];
    const float* scale = (const float*)d_in[2];
    float* out = (float*)d_out;

    // out_size = NB*C*HEIGHT*max_w + NB  ->  max_w recoverable (multiple of 8)
    const int max_w = (out_size - kNB) / (kNB * kC * kHeight);
    const int nq = max_w / 4;

    // Phase 1: pure-write zero-fill (masked suffixes + widths_out tail).
    zerofill_kernel<<<kNB * kC, 256, 0, stream>>>(boxes, scale, out, max_w, nq);

    // Phase 2: active-region gather+store.
    dim3 grid((nq + 63) / 64, kHeight, kNB);
    extract_kernel<<<grid, dim3(64, 1, 1), 0, stream>>>(img, boxes, scale, out, max_w);
}

// Round 10
// 24.784 us; speedup vs baseline: 1.2621x; 1.2621x over previous
//
#include <hip/hip_runtime.h>

// Problem constants (from the reference file)
constexpr int kC = 3;
constexpr int kH = 2048;
constexpr int kW = 2048;
constexpr int kNB = 256;      // N_BOXES
constexpr int kHeight = 32;   // HEIGHT

typedef float f32x4 __attribute__((ext_vector_type(4)));

struct BoxParams {
    float p0x, p0y, p1x, p1y, p2x, p2y, p3x, p3y;
    float curr_w;
    int width;
};

// Bit-identical box math for BOTH block classes (IEEE order, no contraction):
// the active/zero partition depends on `width` agreeing exactly.
__device__ __forceinline__ BoxParams box_params(const float* __restrict__ boxes,
                                                const float* __restrict__ scale,
                                                int b) {
#pragma clang fp contract(off)
    const float s = scale[0];
    const float* bx = boxes + b * 8;
    BoxParams P;
    P.p0x = bx[0] / s; P.p0y = bx[1] / s;
    P.p1x = bx[2] / s; P.p1y = bx[3] / s;
    P.p2x = bx[4] / s; P.p2y = bx[5] / s;
    P.p3x = bx[6] / s; P.p3y = bx[7] / s;
    const float hdx = P.p2x - P.p1x, hdy = P.p2y - P.p1y;
    const float h_dist = sqrtf(hdx * hdx + hdy * hdy);
    const float wdx = P.p1x - P.p0x, wdy = P.p1y - P.p0y;
    const float w_dist = sqrtf(wdx * wdx + wdy * wdy);
    P.width = (int)(32.0f * w_dist / fmaxf(h_dist, 1e-6f));
    P.curr_w = (float)P.width;
    return P;
}

// ONE dispatch, two block classes running concurrently:
//   blocks [0, fillBlocks):      pure-write zero-fill of masked suffixes
//                                (fill-kernel traffic class), + widths tail
//   blocks [fillBlocks, total):  R3-champion gather blocks, active quads only
__global__ __launch_bounds__(64) void extract_fused_kernel(
    const float* __restrict__ img,
    const float* __restrict__ boxes,
    const float* __restrict__ scale,
    float* __restrict__ out,
    int max_w, int nq, int nqc, int fillBlocks)
{
#pragma clang fp contract(off)
    const int bid = blockIdx.x;

    if (bid < fillBlocks) {
        // ---- fill class: (box, channel, 8-row group) ----
        const int rg = bid & 3;
        const int chb = bid >> 2;           // 0..767
        const int b = chb / 3;
        const int ch = chb - b * 3;

        const BoxParams P = box_params(boxes, scale, b);
        const int qstart = (P.width + 3) >> 2;   // first all-zero quad

        if (ch == 0 && rg == 0 && threadIdx.x == 0) {
            out[(size_t)kNB * kC * kHeight * max_w + b] =
                (float)(P.width / 8 * 8 + 8);
        }

        float* plane = out + (size_t)(b * kC + ch) * kHeight * max_w;
        const f32x4 z = {0.f, 0.f, 0.f, 0.f};
#pragma unroll
        for (int rr = 0; rr < 8; ++rr) {
            float* rowp = plane + (size_t)(rg * 8 + rr) * max_w;
            for (int q = qstart + threadIdx.x; q < nq; q += 64) {
                *(f32x4*)(rowp + q * 4) = z;
            }
        }
        return;
    }

    // ---- gather class: R3 structure, active region only ----
    const int gid = bid - fillBlocks;
    const int qc = gid % nqc;
    const int rb = gid / nqc;
    const int r = rb & 31;
    const int b = rb >> 5;

    const BoxParams P = box_params(boxes, scale, b);
    const int c0 = (qc * 64 + threadIdx.x) * 4;
    if (c0 >= P.width) return;            // masked region owned by fill blocks

    const size_t ch_stride = (size_t)kHeight * max_w;
    const size_t obase = (((size_t)b * kC) * (size_t)kHeight + (size_t)r) * (size_t)max_w + (size_t)c0;

    f32x4 o0 = {0.f, 0.f, 0.f, 0.f};
    f32x4 o1 = {0.f, 0.f, 0.f, 0.f};
    f32x4 o2 = {0.f, 0.f, 0.f, 0.f};

    const float y = (float)r / 31.0f;
    const float omy = 1.0f - y;
    const float xden = fmaxf(P.curr_w - 1.0f, 1.0f);
#pragma unroll
    for (int j = 0; j < 4; ++j) {
        const float cf = (float)(c0 + j);
        if (cf < P.curr_w) {
            const float x = cf / xden;
            const float omx = 1.0f - x;
            const float w00 = omx * omy;
            const float w10 = x * omy;
            const float w11 = x * y;
            const float w01 = omx * y;
            const float res_x = w00 * P.p0x + w10 * P.p1x + w11 * P.p2x + w01 * P.p3x;
            const float res_y = w00 * P.p0y + w10 * P.p1y + w11 * P.p2y + w01 * P.p3y;

            const float grid_c = res_x / 2047.0f * 2.0f - 1.0f;
            const float grid_r = res_y / 2047.0f * 2.0f - 1.0f;
            const float fix = rintf((grid_c + 1.0f) * 2047.0f * 0.5f);
            const float fiy = rintf((grid_r + 1.0f) * 2047.0f * 0.5f);
            const bool inb = (fix >= 0.0f) && (fix <= 2047.0f) &&
                             (fiy >= 0.0f) && (fiy <= 2047.0f);
            const int ixc = (int)fminf(fmaxf(fix, 0.0f), 2047.0f);
            const int iyc = (int)fminf(fmaxf(fiy, 0.0f), 2047.0f);

            const size_t ipix = (size_t)iyc * kW + (size_t)ixc;
            const float v0 = img[ipix];
            const float v1 = img[(size_t)kH * kW + ipix];
            const float v2 = img[2 * (size_t)kH * kW + ipix];
            o0[j] = inb ? v0 : 0.0f;
            o1[j] = inb ? v1 : 0.0f;
            o2[j] = inb ? v2 : 0.0f;
        }
    }

    // Boundary quad keeps in-quad zeros; fill blocks start at the NEXT quad,
    // so the two classes write exactly disjoint regions.
    __builtin_nontemporal_store(o0, (f32x4*)(out + obase));
    __builtin_nontemporal_store(o1, (f32x4*)(out + obase + ch_stride));
    __builtin_nontemporal_store(o2, (f32x4*)(out + obase + 2 * ch_stride));
}

extern "C" void kernel_launch(void* const* d_in, const int* in_sizes, int n_in,
                              void* d_out, int out_size, void* d_ws, size_t ws_size,
                              hipStream_t stream) {
    const float* img   = (const float*)d_in[0];
    const float* boxes = (const float*)d_in[1];
    const float* scale = (const float*)d_in[2];
    float* out = (float*)d_out;

    // out_size = NB*C*HEIGHT*max_w + NB  ->  max_w recoverable (multiple of 8)
    const int max_w = (out_size - kNB) / (kNB * kC * kHeight);
    const int nq = max_w / 4;
    const int nqc = (nq + 63) / 64;               // column chunks per row

    const int fillBlocks = kNB * kC * 4;          // (b, ch, 8-row group) = 3072
    const int gatherBlocks = nqc * kHeight * kNB; // R3 grid, linearized
    const int nblocks = fillBlocks + gatherBlocks;

    extract_fused_kernel<<<nblocks, 64, 0, stream>>>(img, boxes, scale, out,
                                                     max_w, nq, nqc, fillBlocks);
}